// Round 1
// baseline (119.340 us; speedup 1.0000x reference)
//
#include <hip/hip_runtime.h>

// Problem constants (from setup_inputs):
//   B=16384, La=50, Lb=20, V=100000, D=64; out = [B, 192] fp32
#define BATCH 16384
#define LA 50
#define LB 20
#define DIM 64

// One wave (64 lanes) per batch row; lane d owns embedding dimension d.
// All index/weight loads are wave-uniform -> scalar loads; each table
// gather is 64 lanes x 4B = one coalesced 256B transaction.
__global__ __launch_bounds__(256) void emb_pool_kernel(
    const int*   __restrict__ ids_single,
    const int*   __restrict__ ids_a,
    const int*   __restrict__ ids_b,
    const float* __restrict__ wa,
    const float* __restrict__ wb,
    const float* __restrict__ table,
    float*       __restrict__ out)
{
    const int wave = __builtin_amdgcn_readfirstlane((int)(threadIdx.x >> 6));
    const int lane = (int)(threadIdx.x & 63);
    const int b    = (int)blockIdx.x * 4 + wave;
    if (b >= BATCH) return;

    float* orow = out + (size_t)b * (3 * DIM);

    // ---- single-id field: straight gather ----
    {
        const int idx = ids_single[b];               // wave-uniform -> s_load
        orow[lane] = table[(size_t)idx * DIM + lane];
    }

    // ---- multi-field A: weighted sum-pool, normalize by sum(w) ----
    {
        const int*   ia = ids_a + (size_t)b * LA;
        const float* wp = wa    + (size_t)b * LA;
        float acc = 0.0f, sw = 0.0f;
#pragma unroll
        for (int l = 0; l < LA; ++l) {
            const float w   = wp[l];                 // wave-uniform
            const int   idx = ia[l];                 // wave-uniform
            sw  += w;
            acc += w * table[(size_t)idx * DIM + lane];
        }
        orow[DIM + lane] = acc / sw;
    }

    // ---- multi-field B ----
    {
        const int*   ib = ids_b + (size_t)b * LB;
        const float* wp = wb    + (size_t)b * LB;
        float acc = 0.0f, sw = 0.0f;
#pragma unroll
        for (int l = 0; l < LB; ++l) {
            const float w   = wp[l];
            const int   idx = ib[l];
            sw  += w;
            acc += w * table[(size_t)idx * DIM + lane];
        }
        orow[2 * DIM + lane] = acc / sw;
    }
}

extern "C" void kernel_launch(void* const* d_in, const int* in_sizes, int n_in,
                              void* d_out, int out_size, void* d_ws, size_t ws_size,
                              hipStream_t stream) {
    const int*   ids_single = (const int*)  d_in[0];
    const int*   ids_a      = (const int*)  d_in[1];
    const int*   ids_b      = (const int*)  d_in[2];
    const float* wa         = (const float*)d_in[3];
    const float* wb         = (const float*)d_in[4];
    const float* table      = (const float*)d_in[5];
    float*       out        = (float*)d_out;

    // 4 waves (rows) per 256-thread block
    const int grid = BATCH / 4;
    emb_pool_kernel<<<grid, 256, 0, stream>>>(ids_single, ids_a, ids_b,
                                              wa, wb, table, out);
}